// Round 1
// baseline (1100.511 us; speedup 1.0000x reference)
//
#include <hip/hip_runtime.h>
#include <math.h>

constexpr int NNODES = 80000;
constexpr int NEDGES = 1280000;

// K0: fold W3/b3 through Wh.
// W35T[k][j] = sum_m Wh[j][m]*W3[m][k]   (stored transposed, [16][64])
// c[j] = bh[j] + sum_m Wh[j][m]*b3[m]
__global__ void k_pre(const float* __restrict__ W3, const float* __restrict__ b3,
                      const float* __restrict__ Wh, const float* __restrict__ bh,
                      float* __restrict__ W35T, float* __restrict__ c) {
    int t = threadIdx.x;            // 1024 threads
    int j = t >> 4, k = t & 15;
    float s = 0.f;
#pragma unroll
    for (int m = 0; m < 64; ++m) s += Wh[j * 64 + m] * W3[m * 16 + k];
    W35T[k * 64 + j] = s;
    if (t < 64) {
        float cc = bh[t];
#pragma unroll
        for (int m = 0; m < 64; ++m) cc += Wh[t * 64 + m] * b3[m];
        c[t] = cc;
    }
}

// K1: per-node  n2 = (h@W1^T + b1 + e@W2^T + b2) @ Wh^T
// one wave per node; weights transposed in LDS (conflict-free reads).
__global__ __launch_bounds__(256) void k_node(
    const float* __restrict__ h, const float* __restrict__ e,
    const float* __restrict__ W1, const float* __restrict__ b1,
    const float* __restrict__ W2, const float* __restrict__ b2,
    const float* __restrict__ Wh, float* __restrict__ n2) {
    __shared__ float sW1T[64 * 64];
    __shared__ float sW2T[32 * 64];
    __shared__ float sWhT[64 * 64];
    __shared__ float sStage[4][64 + 32 + 64];   // per-wave: h | e | npn

    int tid = threadIdx.x;
    for (int idx = tid; idx < 64 * 64; idx += 256) {
        int j = idx >> 6, k = idx & 63;
        sW1T[k * 64 + j] = W1[idx];
        sWhT[k * 64 + j] = Wh[idx];
    }
    for (int idx = tid; idx < 64 * 32; idx += 256) {
        int j = idx >> 5, k = idx & 31;
        sW2T[k * 64 + j] = W2[idx];
    }
    __syncthreads();

    int w = tid >> 6, lane = tid & 63;
    float* hs = &sStage[w][0];
    float* es = &sStage[w][64];
    float* ns = &sStage[w][96];
    int waveId = blockIdx.x * 4 + w;          // 4000 waves, 20 nodes each
    float bb = b1[lane] + b2[lane];

    for (int i = 0; i < 20; ++i) {
        int n = waveId * 20 + i;
        hs[lane] = h[n * 64 + lane];
        if (lane < 32) es[lane] = e[n * 32 + lane];
        __syncthreads();
        float a = bb;
#pragma unroll
        for (int k = 0; k < 64; ++k) a += hs[k] * sW1T[k * 64 + lane];
#pragma unroll
        for (int k = 0; k < 32; ++k) a += es[k] * sW2T[k * 64 + lane];
        ns[lane] = a;
        __syncthreads();
        float o = 0.f;
#pragma unroll
        for (int k = 0; k < 64; ++k) o += ns[k] * sWhT[k * 64 + lane];
        n2[n * 64 + lane] = o;
        __syncthreads();
    }
}

// K2: per-edge  out = elu(n2[src] + n2[dst] + e_ij@W35^T + c) @ Wo^T + bo
// one wave per edge (lane = channel), 8 edges per wave.
__global__ __launch_bounds__(256) void k_edge(
    const float* __restrict__ eij, const int* __restrict__ src, const int* __restrict__ dst,
    const float* __restrict__ n2, const float* __restrict__ W35T, const float* __restrict__ c,
    const float* __restrict__ Wo, const float* __restrict__ bo,
    float* __restrict__ out) {
    __shared__ float sWoT[64 * 64];     // WoT[k][j] = Wo[j][k]
    __shared__ float sW35T[16 * 64];
    __shared__ float sH[4][64];

    int tid = threadIdx.x;
    for (int idx = tid; idx < 64 * 64; idx += 256) {
        int j = idx >> 6, k = idx & 63;
        sWoT[k * 64 + j] = Wo[idx];
    }
    for (int idx = tid; idx < 16 * 64; idx += 256) {
        sW35T[idx] = W35T[idx];         // already transposed in global
    }
    __syncthreads();

    int w = tid >> 6, lane = tid & 63;
    float cj = c[lane], boj = bo[lane];
    constexpr int EPW = 8;
    int base = (blockIdx.x * 4 + w) * EPW;

    for (int i = 0; i < EPW; ++i) {
        int edge = base + i;
        int s = src[edge], d = dst[edge];
        float ev = eij[edge * 16 + (lane & 15)];       // 4 copies across the wave
        float a = cj + n2[s * 64 + lane] + n2[d * 64 + lane];
#pragma unroll
        for (int k = 0; k < 16; ++k) {
            float evk = __shfl(ev, k, 64);
            a += evk * sW35T[k * 64 + lane];
        }
        float hm = a > 0.f ? a : expm1f(a);            // ELU, alpha=1
        sH[w][lane] = hm;
        __syncthreads();
        float o = boj;
#pragma unroll
        for (int k = 0; k < 64; ++k) o += sH[w][k] * sWoT[k * 64 + lane];
        out[edge * 64 + lane] = o;
        __syncthreads();
    }
}

extern "C" void kernel_launch(void* const* d_in, const int* in_sizes, int n_in,
                              void* d_out, int out_size, void* d_ws, size_t ws_size,
                              hipStream_t stream) {
    const float* h   = (const float*)d_in[0];
    const float* e   = (const float*)d_in[1];
    const float* eij = (const float*)d_in[2];
    const int*   src = (const int*)d_in[3];
    const int*   dst = (const int*)d_in[4];
    const float* W1  = (const float*)d_in[5];
    const float* b1  = (const float*)d_in[6];
    const float* W2  = (const float*)d_in[7];
    const float* b2  = (const float*)d_in[8];
    const float* W3  = (const float*)d_in[9];
    const float* b3  = (const float*)d_in[10];
    const float* Wh  = (const float*)d_in[11];
    const float* bh  = (const float*)d_in[12];
    const float* Wo  = (const float*)d_in[13];
    const float* bo  = (const float*)d_in[14];
    float* out = (float*)d_out;

    float* n2   = (float*)d_ws;                     // 80000*64 f32 = 20.48 MB
    float* W35T = n2 + (size_t)NNODES * 64;         // 1024 f32
    float* c    = W35T + 1024;                      // 64 f32

    hipLaunchKernelGGL(k_pre, dim3(1), dim3(1024), 0, stream, W3, b3, Wh, bh, W35T, c);
    hipLaunchKernelGGL(k_node, dim3(1000), dim3(256), 0, stream,
                       h, e, W1, b1, W2, b2, Wh, n2);
    hipLaunchKernelGGL(k_edge, dim3(NEDGES / 32), dim3(256), 0, stream,
                       eij, src, dst, n2, W35T, c, Wo, bo, out);
}

// Round 2
// 588.071 us; speedup vs baseline: 1.8714x; 1.8714x over previous
//
#include <hip/hip_runtime.h>
#include <math.h>

constexpr int NNODES = 80000;
constexpr int NEDGES = 1280000;

// K0: fold W3/b3 through Wh.
// W35R[j*16+k] = sum_m Wh[j][m]*W3[m][k]   (row-major [64][16], lane j reads its row)
// c[j] = bh[j] + sum_m Wh[j][m]*b3[m]
__global__ void k_pre(const float* __restrict__ W3, const float* __restrict__ b3,
                      const float* __restrict__ Wh, const float* __restrict__ bh,
                      float* __restrict__ W35R, float* __restrict__ c) {
    int t = threadIdx.x;            // 1024 threads
    int j = t >> 4, k = t & 15;
    float s = 0.f;
#pragma unroll
    for (int m = 0; m < 64; ++m) s += Wh[j * 64 + m] * W3[m * 16 + k];
    W35R[t] = s;                    // = W35R[j*16+k]
    if (t < 64) {
        float cc = bh[t];
#pragma unroll
        for (int m = 0; m < 64; ++m) cc += Wh[t * 64 + m] * b3[m];
        c[t] = cc;
    }
}

// K1: per-node  n2 = (h@W1^T + b1 + e@W2^T + b2) @ Wh^T
// one wave per node; transposed weights in LDS with stride 65 (conflict-free
// both on the transpose write and the broadcast-column read); no block barriers
// in the node loop (all staging buffers are per-wave).
__global__ __launch_bounds__(256) void k_node(
    const float* __restrict__ h, const float* __restrict__ e,
    const float* __restrict__ W1, const float* __restrict__ b1,
    const float* __restrict__ W2, const float* __restrict__ b2,
    const float* __restrict__ Wh, float* __restrict__ n2) {
    __shared__ float sW1T[64 * 65];
    __shared__ float sW2T[32 * 65];
    __shared__ float sWhT[64 * 65];
    __shared__ float sStage[4][160];   // per-wave: h[64] | e[32] | npn[64]

    int tid = threadIdx.x;
    for (int idx = tid; idx < 64 * 64; idx += 256) {
        int j = idx >> 6, k = idx & 63;
        sW1T[k * 65 + j] = W1[idx];
        sWhT[k * 65 + j] = Wh[idx];
    }
    for (int idx = tid; idx < 64 * 32; idx += 256) {
        int j = idx >> 5, k = idx & 31;
        sW2T[k * 65 + j] = W2[idx];
    }
    __syncthreads();

    int w = tid >> 6, lane = tid & 63;
    float* hs = &sStage[w][0];
    float* es = &sStage[w][64];
    float* ns = &sStage[w][96];
    int waveId = blockIdx.x * 4 + w;          // 4000 waves, 20 nodes each
    float bb = b1[lane] + b2[lane];

    for (int i = 0; i < 20; ++i) {
        int n = waveId * 20 + i;
        hs[lane] = h[n * 64 + lane];
        if (lane < 32) es[lane] = e[n * 32 + lane];
        float a = bb;
#pragma unroll
        for (int k = 0; k < 64; ++k) a += hs[k] * sW1T[k * 65 + lane];
#pragma unroll
        for (int k = 0; k < 32; ++k) a += es[k] * sW2T[k * 65 + lane];
        ns[lane] = a;
        float o = 0.f;
#pragma unroll
        for (int k = 0; k < 64; ++k) o += ns[k] * sWhT[k * 65 + lane];
        n2[n * 64 + lane] = o;
    }
}

// K2: per-edge  out = elu(n2[src] + n2[dst] + e_ij@W35^T + c) @ Wo^T + bo
// Lane j owns output channel j. Wo row j (64 f32) and W35 row j (16 f32) live
// in REGISTERS (contiguous per-lane global loads, one-time). Only cross-lane
// traffic: hmid broadcast through a per-wave 256B LDS buffer (no barriers).
// Each wave owns 250 contiguous edges; next edge's gathers prefetched.
__global__ __launch_bounds__(256, 4) void k_edge(
    const float* __restrict__ eij, const int* __restrict__ src, const int* __restrict__ dst,
    const float* __restrict__ n2, const float* __restrict__ W35R, const float* __restrict__ c,
    const float* __restrict__ Wo, const float* __restrict__ bo,
    float* __restrict__ out) {
    __shared__ float sH[4][64];

    int tid = threadIdx.x;
    int w = tid >> 6, lane = tid & 63;

    float wo[64];
    const float4* worow = (const float4*)(Wo + lane * 64);
#pragma unroll
    for (int k4 = 0; k4 < 16; ++k4) {
        float4 t = worow[k4];
        wo[4 * k4 + 0] = t.x; wo[4 * k4 + 1] = t.y;
        wo[4 * k4 + 2] = t.z; wo[4 * k4 + 3] = t.w;
    }
    float w35[16];
    const float4* wr = (const float4*)(W35R + lane * 16);
#pragma unroll
    for (int k4 = 0; k4 < 4; ++k4) {
        float4 t = wr[k4];
        w35[4 * k4 + 0] = t.x; w35[4 * k4 + 1] = t.y;
        w35[4 * k4 + 2] = t.z; w35[4 * k4 + 3] = t.w;
    }
    float cj = c[lane], boj = bo[lane];
    float* sHw = sH[w];
    const float4* sH4 = (const float4*)sHw;

    constexpr int EPW = 250;                       // 1280 blk * 4 waves * 250 = 1.28M
    int e0 = (blockIdx.x * 4 + w) * EPW;

    int s_ = src[e0], d_ = dst[e0];
    float ev_ = eij[(size_t)e0 * 16 + (lane & 15)];
    float na_ = n2[(size_t)s_ * 64 + lane];
    float nb_ = n2[(size_t)d_ * 64 + lane];

    for (int i = 0; i < EPW; ++i) {
        int e = e0 + i;
        int en = (i + 1 < EPW) ? (e + 1) : e;      // branchless, in-bounds prefetch
        int s2 = src[en], d2 = dst[en];
        float ev2 = eij[(size_t)en * 16 + (lane & 15)];
        float na2 = n2[(size_t)s2 * 64 + lane];
        float nb2 = n2[(size_t)d2 * 64 + lane];

        float a = cj + na_ + nb_;
#pragma unroll
        for (int k = 0; k < 16; ++k)
            a = fmaf(__shfl(ev_, k, 64), w35[k], a);
        float hm = a > 0.f ? a : expm1f(a);        // ELU alpha=1
        sHw[lane] = hm;                            // same-wave LDS: no barrier
        float o = boj;
#pragma unroll
        for (int k4 = 0; k4 < 16; ++k4) {
            float4 hv = sH4[k4];                   // broadcast read
            o = fmaf(hv.x, wo[4 * k4 + 0], o);
            o = fmaf(hv.y, wo[4 * k4 + 1], o);
            o = fmaf(hv.z, wo[4 * k4 + 2], o);
            o = fmaf(hv.w, wo[4 * k4 + 3], o);
        }
        out[(size_t)e * 64 + lane] = o;
        s_ = s2; d_ = d2; ev_ = ev2; na_ = na2; nb_ = nb2;
    }
}

extern "C" void kernel_launch(void* const* d_in, const int* in_sizes, int n_in,
                              void* d_out, int out_size, void* d_ws, size_t ws_size,
                              hipStream_t stream) {
    const float* h   = (const float*)d_in[0];
    const float* e   = (const float*)d_in[1];
    const float* eij = (const float*)d_in[2];
    const int*   src = (const int*)d_in[3];
    const int*   dst = (const int*)d_in[4];
    const float* W1  = (const float*)d_in[5];
    const float* b1  = (const float*)d_in[6];
    const float* W2  = (const float*)d_in[7];
    const float* b2  = (const float*)d_in[8];
    const float* W3  = (const float*)d_in[9];
    const float* b3  = (const float*)d_in[10];
    const float* Wh  = (const float*)d_in[11];
    const float* bh  = (const float*)d_in[12];
    const float* Wo  = (const float*)d_in[13];
    const float* bo  = (const float*)d_in[14];
    float* out = (float*)d_out;

    float* n2   = (float*)d_ws;                     // 80000*64 f32 = 20.48 MB
    float* W35R = n2 + (size_t)NNODES * 64;         // 1024 f32, row-major [64][16]
    float* c    = W35R + 1024;                      // 64 f32

    hipLaunchKernelGGL(k_pre, dim3(1), dim3(1024), 0, stream, W3, b3, Wh, bh, W35R, c);
    hipLaunchKernelGGL(k_node, dim3(1000), dim3(256), 0, stream,
                       h, e, W1, b1, W2, b2, Wh, n2);
    hipLaunchKernelGGL(k_edge, dim3(NEDGES / 1000), dim3(256), 0, stream,
                       eij, src, dst, n2, W35R, c, Wo, bo, out);
}

// Round 3
// 265.091 us; speedup vs baseline: 4.1514x; 2.2184x over previous
//
#include <hip/hip_runtime.h>
#include <math.h>

constexpr int NNODES = 80000;
constexpr int NEDGES = 1280000;

typedef __attribute__((ext_vector_type(8))) short bf16x8;
typedef __attribute__((ext_vector_type(16))) float f32x16;

__device__ __forceinline__ short f2b(float f) {
    unsigned u = __builtin_bit_cast(unsigned, f);
    u = u + 0x7FFFu + ((u >> 16) & 1u);          // RNE to bf16
    return (short)(u >> 16);
}

// K0: fold W3/b3 through Wh; emit W35 and Wo as bf16 in MFMA B-fragment lane
// order for v_mfma_f32_32x32x16_bf16:  B[k][j] held by lane l = (j&31) with
// j-block b, k = 8*(l>>5)+i (+16*ks for Wo's K=64).
// W35F[b*512 + l*8 + i] = bf16(W35T[8*(l>>5)+i][32b+(l&31)])
// WoF[b*2048 + ks*512 + l*8 + i] = bf16(Wo[32b+(l&31)][16ks+8*(l>>5)+i])
// c[j] = bh[j] + sum_m Wh[j][m]*b3[m]
__global__ void k_pre(const float* __restrict__ W3, const float* __restrict__ b3,
                      const float* __restrict__ Wh, const float* __restrict__ bh,
                      const float* __restrict__ Wo,
                      short* __restrict__ W35F, short* __restrict__ WoF,
                      float* __restrict__ c) {
    int t = threadIdx.x;            // 1024 threads
    {
        int b = t >> 9, l = (t >> 3) & 63, i = t & 7;
        int k = 8 * (l >> 5) + i;
        int j = 32 * b + (l & 31);
        float s = 0.f;
#pragma unroll
        for (int m = 0; m < 64; ++m) s += Wh[j * 64 + m] * W3[m * 16 + k];
        W35F[t] = f2b(s);
    }
#pragma unroll
    for (int q = 0; q < 4; ++q) {
        int idx = q * 1024 + t;
        int b  = idx >> 11;
        int ks = (idx >> 9) & 3;
        int l  = (idx >> 3) & 63;
        int i  = idx & 7;
        int k  = 16 * ks + 8 * (l >> 5) + i;
        int j  = 32 * b + (l & 31);
        WoF[idx] = f2b(Wo[j * 64 + k]);
    }
    if (t < 64) {
        float cc = bh[t];
#pragma unroll
        for (int m = 0; m < 64; ++m) cc += Wh[t * 64 + m] * b3[m];
        c[t] = cc;
    }
}

// K1: per-node  n2 = (h@W1^T + b1 + e@W2^T + b2) @ Wh^T   (unchanged)
__global__ __launch_bounds__(256) void k_node(
    const float* __restrict__ h, const float* __restrict__ e,
    const float* __restrict__ W1, const float* __restrict__ b1,
    const float* __restrict__ W2, const float* __restrict__ b2,
    const float* __restrict__ Wh, float* __restrict__ n2) {
    __shared__ float sW1T[64 * 65];
    __shared__ float sW2T[32 * 65];
    __shared__ float sWhT[64 * 65];
    __shared__ float sStage[4][160];

    int tid = threadIdx.x;
    for (int idx = tid; idx < 64 * 64; idx += 256) {
        int j = idx >> 6, k = idx & 63;
        sW1T[k * 65 + j] = W1[idx];
        sWhT[k * 65 + j] = Wh[idx];
    }
    for (int idx = tid; idx < 64 * 32; idx += 256) {
        int j = idx >> 5, k = idx & 31;
        sW2T[k * 65 + j] = W2[idx];
    }
    __syncthreads();

    int w = tid >> 6, lane = tid & 63;
    float* hs = &sStage[w][0];
    float* es = &sStage[w][64];
    float* ns = &sStage[w][96];
    int waveId = blockIdx.x * 4 + w;
    float bb = b1[lane] + b2[lane];

    for (int i = 0; i < 20; ++i) {
        int n = waveId * 20 + i;
        hs[lane] = h[n * 64 + lane];
        if (lane < 32) es[lane] = e[n * 32 + lane];
        float a = bb;
#pragma unroll
        for (int k = 0; k < 64; ++k) a += hs[k] * sW1T[k * 65 + lane];
#pragma unroll
        for (int k = 0; k < 32; ++k) a += es[k] * sW2T[k * 65 + lane];
        ns[lane] = a;
        float o = 0.f;
#pragma unroll
        for (int k = 0; k < 64; ++k) o += ns[k] * sWhT[k * 65 + lane];
        n2[n * 64 + lane] = o;
    }
}

// K2: per-edge MLP via MFMA. One wave = 32-edge tile, 4 tiles/wave.
//  A1 = bf16(eij tile [32x16])      -> pre = A1 @ W35F  (2 MFMA, K=16)
//  g  = c + n2[src] + n2[dst]       (lane=channel, coalesced; LDS transpose)
//  hmid = elu(pre + g)  (f32, acc layout) -> bf16 -> LDS [32][72]
//  out = hmid @ WoF + bo            (8 MFMA, K=64), nontemporal stores.
__global__ __launch_bounds__(256, 3) void k_edge(
    const float* __restrict__ eij, const int* __restrict__ src, const int* __restrict__ dst,
    const float* __restrict__ n2, const short* __restrict__ W35F, const short* __restrict__ WoF,
    const float* __restrict__ c, const float* __restrict__ bo,
    float* __restrict__ out) {
    __shared__ __align__(16) char smem[4][8320];   // per-wave: g[32][65] f32, reused as hA[32][72] bf16

    int tid = threadIdx.x;
    int w = tid >> 6, lane = tid & 63;
    int hf = lane >> 5;          // k-half / row-half selector
    int l31 = lane & 31;

    float* g  = (float*)smem[w];
    short* hA = (short*)smem[w];

    bf16x8 w35f0 = *(const bf16x8*)(W35F + (0 * 64 + lane) * 8);
    bf16x8 w35f1 = *(const bf16x8*)(W35F + (1 * 64 + lane) * 8);
    bf16x8 wof[2][4];
#pragma unroll
    for (int b = 0; b < 2; ++b)
#pragma unroll
        for (int ks = 0; ks < 4; ++ks)
            wof[b][ks] = *(const bf16x8*)(WoF + ((b * 4 + ks) * 64 + lane) * 8);

    float cj  = c[lane];
    float bo0 = bo[l31], bo1 = bo[l31 + 32];

    int waveG = blockIdx.x * 4 + w;
    for (int tt = 0; tt < 4; ++tt) {
        int base = (waveG * 4 + tt) * 32;
        asm volatile("" ::: "memory");             // vs prev tile's hA reads

        int sv = src[base + l31];
        int dv = dst[base + l31];
        const float* ep = eij + ((size_t)(base + l31) * 16 + hf * 8);
        float4 e0 = *(const float4*)ep;
        float4 e1 = *(const float4*)(ep + 4);
        bf16x8 ea = { f2b(e0.x), f2b(e0.y), f2b(e0.z), f2b(e0.w),
                      f2b(e1.x), f2b(e1.y), f2b(e1.z), f2b(e1.w) };

#pragma unroll 16
        for (int e = 0; e < 32; ++e) {
            int s = __builtin_amdgcn_readlane(sv, e);
            int d = __builtin_amdgcn_readlane(dv, e);
            float na = n2[(size_t)s * 64 + lane];
            float nb = n2[(size_t)d * 64 + lane];
            g[e * 65 + lane] = cj + na + nb;       // bank = (e+lane)&31: 2-way, free
        }
        asm volatile("" ::: "memory");

        const f32x16 zero = {0,0,0,0,0,0,0,0,0,0,0,0,0,0,0,0};
        f32x16 h0 = __builtin_amdgcn_mfma_f32_32x32x16_bf16(ea, w35f0, zero, 0, 0, 0);
        f32x16 h1 = __builtin_amdgcn_mfma_f32_32x32x16_bf16(ea, w35f1, zero, 0, 0, 0);
#pragma unroll
        for (int r = 0; r < 16; ++r) {
            int row = (r & 3) + 8 * (r >> 2) + 4 * hf;
            float v0 = h0[r] + g[row * 65 + l31];
            float v1 = h1[r] + g[row * 65 + l31 + 32];
            h0[r] = v0 > 0.f ? v0 : __expf(v0) - 1.f;   // ELU alpha=1
            h1[r] = v1 > 0.f ? v1 : __expf(v1) - 1.f;
        }
        asm volatile("" ::: "memory");             // all g reads before hA writes
#pragma unroll
        for (int r = 0; r < 16; ++r) {
            int row = (r & 3) + 8 * (r >> 2) + 4 * hf;
            hA[row * 72 + l31]      = f2b(h0[r]);
            hA[row * 72 + l31 + 32] = f2b(h1[r]);
        }
        asm volatile("" ::: "memory");             // hA writes before A2 reads

        f32x16 o0 = zero, o1 = zero;
#pragma unroll
        for (int ks = 0; ks < 4; ++ks) {
            bf16x8 a2 = *(const bf16x8*)(hA + l31 * 72 + ks * 16 + hf * 8);
            o0 = __builtin_amdgcn_mfma_f32_32x32x16_bf16(a2, wof[0][ks], o0, 0, 0, 0);
            o1 = __builtin_amdgcn_mfma_f32_32x32x16_bf16(a2, wof[1][ks], o1, 0, 0, 0);
        }
#pragma unroll
        for (int r = 0; r < 16; ++r) {
            int row = (r & 3) + 8 * (r >> 2) + 4 * hf;
            size_t off = (size_t)(base + row) * 64 + l31;
            __builtin_nontemporal_store(o0[r] + bo0, out + off);
            __builtin_nontemporal_store(o1[r] + bo1, out + off + 32);
        }
    }
}

extern "C" void kernel_launch(void* const* d_in, const int* in_sizes, int n_in,
                              void* d_out, int out_size, void* d_ws, size_t ws_size,
                              hipStream_t stream) {
    const float* h   = (const float*)d_in[0];
    const float* e   = (const float*)d_in[1];
    const float* eij = (const float*)d_in[2];
    const int*   src = (const int*)d_in[3];
    const int*   dst = (const int*)d_in[4];
    const float* W1  = (const float*)d_in[5];
    const float* b1  = (const float*)d_in[6];
    const float* W2  = (const float*)d_in[7];
    const float* b2  = (const float*)d_in[8];
    const float* W3  = (const float*)d_in[9];
    const float* b3  = (const float*)d_in[10];
    const float* Wh  = (const float*)d_in[11];
    const float* bh  = (const float*)d_in[12];
    const float* Wo  = (const float*)d_in[13];
    const float* bo  = (const float*)d_in[14];
    float* out = (float*)d_out;

    float* n2   = (float*)d_ws;                     // 80000*64 f32 = 20.48 MB
    short* W35F = (short*)(n2 + (size_t)NNODES * 64);  // 1024 bf16 (B-frag order)
    short* WoF  = W35F + 1024;                      // 4096 bf16 (B-frag order)
    float* c    = (float*)(WoF + 4096);             // 64 f32

    hipLaunchKernelGGL(k_pre, dim3(1), dim3(1024), 0, stream, W3, b3, Wh, bh, Wo, W35F, WoF, c);
    hipLaunchKernelGGL(k_node, dim3(1000), dim3(256), 0, stream,
                       h, e, W1, b1, W2, b2, Wh, n2);
    // 2500 blocks * 4 waves * 4 tiles * 32 edges = 1,280,000
    hipLaunchKernelGGL(k_edge, dim3(2500), dim3(256), 0, stream,
                       eij, src, dst, n2, W35F, WoF, c, bo, out);
}